// Round 7
// baseline (241.242 us; speedup 1.0000x reference)
//
#include <hip/hip_runtime.h>

#define C 192
#define H 56
#define W 56
#define HW (H * W)
#define CHW (C * HW)
#define NB 32
#define PPS 36
#define EPSLN 1e-5f

// ---- DPP cross-lane helpers (16-lane rows == our sub-groups) ----
#define CTL_SHL1 0x101
#define CTL_SHL2 0x102
#define CTL_SHR1 0x111
#define CTL_SHR2 0x112

template<int CTRL>
__device__ __forceinline__ float dppf(float v) {
    return __int_as_float(__builtin_amdgcn_update_dpp(
        0, __float_as_int(v), CTRL, 0xf, 0xf, true));
}

struct __attribute__((aligned(16))) f4 { float x, y, z, w; };

__device__ __forceinline__ f4 f4z() { return {0.f, 0.f, 0.f, 0.f}; }
__device__ __forceinline__ f4 f4b(float s) { return {s, s, s, s}; }
__device__ __forceinline__ f4 fma4(f4 a, float s, f4 c) {
    return { fmaf(a.x, s, c.x), fmaf(a.y, s, c.y),
             fmaf(a.z, s, c.z), fmaf(a.w, s, c.w) };
}
// lane l holds w in [4l, 4l+4); shifted view: comp k = row[4l+k+s]
__device__ __forceinline__ f4 shp1(f4 v){ return { v.y, v.z, v.w, dppf<CTL_SHL1>(v.x) }; }
__device__ __forceinline__ f4 shm1(f4 v){ return { dppf<CTL_SHR1>(v.w), v.x, v.y, v.z }; }
__device__ __forceinline__ f4 shp3(f4 v){ return { v.w, dppf<CTL_SHL1>(v.x),
                                                   dppf<CTL_SHL1>(v.y), dppf<CTL_SHL1>(v.z) }; }
__device__ __forceinline__ f4 shm3(f4 v){ return { dppf<CTL_SHR1>(v.y), dppf<CTL_SHR1>(v.z),
                                                   dppf<CTL_SHR1>(v.w), v.x }; }
__device__ __forceinline__ f4 shp5(f4 v){ return { dppf<CTL_SHL1>(v.y), dppf<CTL_SHL1>(v.z),
                                                   dppf<CTL_SHL1>(v.w), dppf<CTL_SHL2>(v.x) }; }
__device__ __forceinline__ f4 shm5(f4 v){ return { dppf<CTL_SHR2>(v.w), dppf<CTL_SHR1>(v.x),
                                                   dppf<CTL_SHR1>(v.y), dppf<CTL_SHR1>(v.z) }; }

__device__ __forceinline__ f4 prelu_acc(f4 acc, f4 y, float a) {
    acc.x += fmaxf(y.x, 0.f) + a * fminf(y.x, 0.f);
    acc.y += fmaxf(y.y, 0.f) + a * fminf(y.y, 0.f);
    acc.z += fmaxf(y.z, 0.f) + a * fminf(y.z, 0.f);
    acc.w += fmaxf(y.w, 0.f) + a * fminf(y.w, 0.f);
    return acc;
}

// ---- prep: fold params into packed 36-float records (d_ws) ----
__global__ void prep_kernel(const float* __restrict__ bias,
                            const float* __restrict__ conv_w,
                            const float* __restrict__ conv_b,
                            const float* __restrict__ move1,
                            const float* __restrict__ alpha,
                            const float* __restrict__ move2,
                            const float* __restrict__ ln_g,
                            const float* __restrict__ ln_b,
                            float* __restrict__ pp, float* __restrict__ gb) {
    const int c = threadIdx.x;
    if (c >= C) return;
    float* pc = pp + c * PPS;
    #pragma unroll
    for (int i = 0; i < 3; ++i)
        #pragma unroll
        for (int k = 0; k < 9; ++k)
            pc[i * 9 + k] = conv_w[(size_t)(i * C + c) * 9 + k];
    #pragma unroll
    for (int i = 0; i < 3; ++i) {
        pc[27 + i] = conv_b[i * C + c] - move1[i * C + c];
        pc[30 + i] = alpha[i * C + c];
    }
    pc[33] = bias[c];
    pc[34] = move2[0 * C + c] + move2[1 * C + c] + move2[2 * C + c];
    pc[35] = 0.f;
    gb[2 * c]     = ln_g[c];
    gb[2 * c + 1] = ln_b[c];
}

// Issue NEXT channel's weights (into wnv) and rows (into nxt). Placed BEFORE
// the current step's compute so the ~300cy L2 latency hides under ~1100cy of
// VALU. This is the r7 change: weights were previously loaded at step start
// and consumed immediately -> per-step dependent stall, synchronized across
// all waves (occupancy couldn't hide it -- r6 proved +33% waves = +0%).
#define PREFETCH_STEP(JN)                                                    \
    {                                                                        \
        const float* pn_ = pp + (cbase + 4 * (JN)) * PPS;                    \
        _Pragma("unroll")                                                    \
        for (int k = 0; k < 9; ++k)                                          \
            *(f4*)(wnv + 4 * k) = *(const f4*)(pn_ + 4 * k);                 \
        const float* xn_ = xc + (size_t)(4 * (JN)) * HW;                     \
        _Pragma("unroll")                                                    \
        for (int k = 0; k < 7; ++k)                                          \
            nxt[k] = vr[k] ? *(const f4*)(xn_ + ro[k]) : f4z();              \
    }

// Compute one channel step purely from register-resident wcv[36] + cur[7].
// All wcv/cur indices compile-time constant -> stays in registers.
#define COMPUTE_STEP(ACC_OUT)                                                \
    {                                                                        \
        const float bsa_ = wcv[33] * act_f;                                  \
        f4 r[7];                                                             \
        _Pragma("unroll")                                                    \
        for (int k = 0; k < 7; ++k) {                                        \
            const float bk_ = vr[k] ? bsa_ : 0.f;                            \
            r[k].x = fmaf(cur[k].x, act_f, bk_);                             \
            r[k].y = fmaf(cur[k].y, act_f, bk_);                             \
            r[k].z = fmaf(cur[k].z, act_f, bk_);                             \
            r[k].w = fmaf(cur[k].w, act_f, bk_);                             \
        }                                                                    \
        f4 acc_ = f4b(wcv[34]);                                              \
        {   /* d = 1: rows r[2],r[3],r[4], weights wcv[0..8] */              \
            f4 y = f4b(wcv[27]);                                             \
            y = fma4(shm1(r[2]), wcv[0], y);                                 \
            y = fma4(r[2],       wcv[1], y);                                 \
            y = fma4(shp1(r[2]), wcv[2], y);                                 \
            y = fma4(shm1(r[3]), wcv[3], y);                                 \
            y = fma4(r[3],       wcv[4], y);                                 \
            y = fma4(shp1(r[3]), wcv[5], y);                                 \
            y = fma4(shm1(r[4]), wcv[6], y);                                 \
            y = fma4(r[4],       wcv[7], y);                                 \
            y = fma4(shp1(r[4]), wcv[8], y);                                 \
            acc_ = prelu_acc(acc_, y, wcv[30]);                              \
        }                                                                    \
        {   /* d = 3: rows r[1],r[3],r[5], weights wcv[9..17] */             \
            f4 y = f4b(wcv[28]);                                             \
            y = fma4(shm3(r[1]), wcv[9],  y);                                \
            y = fma4(r[1],       wcv[10], y);                                \
            y = fma4(shp3(r[1]), wcv[11], y);                                \
            y = fma4(shm3(r[3]), wcv[12], y);                                \
            y = fma4(r[3],       wcv[13], y);                                \
            y = fma4(shp3(r[3]), wcv[14], y);                                \
            y = fma4(shm3(r[5]), wcv[15], y);                                \
            y = fma4(r[5],       wcv[16], y);                                \
            y = fma4(shp3(r[5]), wcv[17], y);                                \
            acc_ = prelu_acc(acc_, y, wcv[31]);                              \
        }                                                                    \
        {   /* d = 5: rows r[0],r[3],r[6], weights wcv[18..26] */            \
            f4 y = f4b(wcv[29]);                                             \
            y = fma4(shm5(r[0]), wcv[18], y);                                \
            y = fma4(r[0],       wcv[19], y);                                \
            y = fma4(shp5(r[0]), wcv[20], y);                                \
            y = fma4(shm5(r[3]), wcv[21], y);                                \
            y = fma4(r[3],       wcv[22], y);                                \
            y = fma4(shp5(r[3]), wcv[23], y);                                \
            y = fma4(shm5(r[6]), wcv[24], y);                                \
            y = fma4(r[6],       wcv[25], y);                                \
            y = fma4(shp5(r[6]), wcv[26], y);                                \
            acc_ = prelu_acc(acc_, y, wcv[32]);                              \
        }                                                                    \
        s4.x += acc_.x; s4.y += acc_.y; s4.z += acc_.z; s4.w += acc_.w;      \
        q4.x = fmaf(acc_.x, acc_.x, q4.x); q4.y = fmaf(acc_.y, acc_.y, q4.y);\
        q4.z = fmaf(acc_.z, acc_.z, q4.z); q4.w = fmaf(acc_.w, acc_.w, q4.w);\
        (ACC_OUT) = acc_;                                                    \
    }

#define ROTATE_ALL()                                                         \
    {                                                                        \
        _Pragma("unroll")                                                    \
        for (int k = 0; k < 7; ++k) cur[k] = nxt[k];                         \
        _Pragma("unroll")                                                    \
        for (int k = 0; k < 36; ++k) wcv[k] = wnv[k];                        \
    }

// Full software pipeline: weights AND rows double-buffered one step ahead.
// Natural VGPR ~140-150 -> launch_bounds(256,3) (budget ~170, the tier r0
// proved spill-free). LDS back to the simple full stash: 45056 B, 3 blk/CU.
// Occupancy ~27% is fine -- r6 proved occupancy is not the lever; the
// synchronized per-step weight-load stall is.
__global__ __launch_bounds__(256, 3) void msgdc_kernel(
    const float* __restrict__ x, const float* __restrict__ pp,
    const float* __restrict__ gb, float* __restrict__ out)
{
    __shared__ float tile[C * W];        // 43008 B: pre-LN stash, all 12 steps
    __shared__ float sred[4][16][8];     // cross-wave LN partials (2048 B)

    const int t = threadIdx.x;
    const int lane = t & 63;
    const int wv = __builtin_amdgcn_readfirstlane(t >> 6);
    const int l = lane & 15;             // position within 16-lane sub-group
    const bool act = (l < 14);           // 14 lanes x float4 = 56 pixels
    const float act_f = act ? 1.f : 0.f;
    const int lw = act ? 4 * l : 52;     // clamped (safe) w offset for idle lanes

    const int blk = blockIdx.x;
    const int gid = (blk & 7) * 224 + (blk >> 3);   // XCD-contiguous (b,h)
    const int b = gid / H;
    const int h = gid - b * H;

    // uniform row validity, offsets {-5,-3,-1,0,+1,+3,+5}
    const bool vr[7] = { h >= 5, h >= 3, h >= 1, true,
                         h <= H - 2, h <= H - 4, h <= H - 6 };
    const int  ro[7] = { -5 * W, -3 * W, -1 * W, 0, 1 * W, 3 * W, 5 * W };

    const int cbase = wv * 48 + (lane >> 4);        // channel for j=0
    const float* xc = x + (size_t)b * CHW + (size_t)cbase * HW + h * W + lw;

    f4 cur[7], nxt[7];
    float wcv[36], wnv[36];

    // prologue: weights + rows for j=0
    {
        const float* p0_ = pp + cbase * PPS;
        #pragma unroll
        for (int k = 0; k < 9; ++k)
            *(f4*)(wcv + 4 * k) = *(const f4*)(p0_ + 4 * k);
        #pragma unroll
        for (int k = 0; k < 7; ++k)
            cur[k] = vr[k] ? *(const f4*)(xc + ro[k]) : f4z();
    }

    f4 s4 = f4z(), q4 = f4z();

    #pragma unroll 2
    for (int j = 0; j < 12; ++j) {
        if (j < 11) PREFETCH_STEP(j + 1);
        f4 acc;
        COMPUTE_STEP(acc);
        if (act) *(f4*)(tile + (cbase + 4 * j) * W + lw) = acc;
        if (j < 11) ROTATE_ALL();
    }

    // ---- LN reduction: cross-group (xor16/32 keeps l fixed), then cross-wave ----
    #pragma unroll
    for (int m = 16; m <= 32; m <<= 1) {
        s4.x += __shfl_xor(s4.x, m, 64); s4.y += __shfl_xor(s4.y, m, 64);
        s4.z += __shfl_xor(s4.z, m, 64); s4.w += __shfl_xor(s4.w, m, 64);
        q4.x += __shfl_xor(q4.x, m, 64); q4.y += __shfl_xor(q4.y, m, 64);
        q4.z += __shfl_xor(q4.z, m, 64); q4.w += __shfl_xor(q4.w, m, 64);
    }
    if (lane < 14) {
        *(f4*)&sred[wv][lane][0] = s4;
        *(f4*)&sred[wv][lane][4] = q4;
    }
    __syncthreads();

    f4 S = f4z(), Q = f4z();
    #pragma unroll
    for (int w2 = 0; w2 < 4; ++w2) {
        const f4 a = *(const f4*)&sred[w2][l][0];
        const f4 bq = *(const f4*)&sred[w2][l][4];
        S.x += a.x; S.y += a.y; S.z += a.z; S.w += a.w;
        Q.x += bq.x; Q.y += bq.y; Q.z += bq.z; Q.w += bq.w;
    }
    const float inv = 1.f / (float)C;
    f4 mean = { S.x * inv, S.y * inv, S.z * inv, S.w * inv };
    f4 rstd = { rsqrtf(Q.x * inv - mean.x * mean.x + EPSLN),
                rsqrtf(Q.y * inv - mean.y * mean.y + EPSLN),
                rsqrtf(Q.z * inv - mean.z * mean.z + EPSLN),
                rsqrtf(Q.w * inv - mean.w * mean.w + EPSLN) };

    float* ob = out + (size_t)b * CHW + (size_t)cbase * HW + h * W + lw;
    #pragma unroll 2
    for (int j = 0; j < 12; ++j) {
        const int c = cbase + 4 * j;
        const float ga = gb[2 * c], be = gb[2 * c + 1];
        if (act) {
            const f4 v = *(const f4*)(tile + c * W + lw);
            f4 o;
            o.x = fmaf((v.x - mean.x) * rstd.x, ga, be);
            o.y = fmaf((v.y - mean.y) * rstd.y, ga, be);
            o.z = fmaf((v.z - mean.z) * rstd.z, ga, be);
            o.w = fmaf((v.w - mean.w) * rstd.w, ga, be);
            *(f4*)(ob + (size_t)(4 * j) * HW) = o;
        }
    }
}

extern "C" void kernel_launch(void* const* d_in, const int* in_sizes, int n_in,
                              void* d_out, int out_size, void* d_ws, size_t ws_size,
                              hipStream_t stream) {
    const float* x       = (const float*)d_in[0];
    const float* bias    = (const float*)d_in[1];
    const float* conv_w  = (const float*)d_in[2];
    const float* conv_b  = (const float*)d_in[3];
    const float* move1   = (const float*)d_in[4];
    const float* alpha   = (const float*)d_in[5];
    const float* move2   = (const float*)d_in[6];
    const float* ln_g    = (const float*)d_in[7];
    const float* ln_b    = (const float*)d_in[8];
    float* out = (float*)d_out;

    float* pp = (float*)d_ws;                 // 192*36 floats
    float* gbp = pp + C * PPS;                // 192*2 floats

    prep_kernel<<<1, 256, 0, stream>>>(bias, conv_w, conv_b, move1, alpha,
                                       move2, ln_g, ln_b, pp, gbp);
    msgdc_kernel<<<NB * H, 256, 0, stream>>>(x, pp, gbp, out);
}

// Round 8
// 202.590 us; speedup vs baseline: 1.1908x; 1.1908x over previous
//
#include <hip/hip_runtime.h>

#define C 192
#define H 56
#define W 56
#define HW (H * W)
#define CHW (C * HW)
#define NB 32
#define PPS 36
#define EPSLN 1e-5f

// ---- DPP cross-lane helpers (16-lane rows == our sub-groups) ----
#define CTL_SHL1 0x101
#define CTL_SHL2 0x102
#define CTL_SHR1 0x111
#define CTL_SHR2 0x112

template<int CTRL>
__device__ __forceinline__ float dppf(float v) {
    return __int_as_float(__builtin_amdgcn_update_dpp(
        0, __float_as_int(v), CTRL, 0xf, 0xf, true));
}

struct __attribute__((aligned(16))) f4 { float x, y, z, w; };

__device__ __forceinline__ f4 f4z() { return {0.f, 0.f, 0.f, 0.f}; }
__device__ __forceinline__ f4 f4b(float s) { return {s, s, s, s}; }
__device__ __forceinline__ f4 fma4(f4 a, float s, f4 c) {
    return { fmaf(a.x, s, c.x), fmaf(a.y, s, c.y),
             fmaf(a.z, s, c.z), fmaf(a.w, s, c.w) };
}
// lane l holds w in [4l, 4l+4); shifted view: comp k = row[4l+k+s]
__device__ __forceinline__ f4 shp1(f4 v){ return { v.y, v.z, v.w, dppf<CTL_SHL1>(v.x) }; }
__device__ __forceinline__ f4 shm1(f4 v){ return { dppf<CTL_SHR1>(v.w), v.x, v.y, v.z }; }
__device__ __forceinline__ f4 shp3(f4 v){ return { v.w, dppf<CTL_SHL1>(v.x),
                                                   dppf<CTL_SHL1>(v.y), dppf<CTL_SHL1>(v.z) }; }
__device__ __forceinline__ f4 shm3(f4 v){ return { dppf<CTL_SHR1>(v.y), dppf<CTL_SHR1>(v.z),
                                                   dppf<CTL_SHR1>(v.w), v.x }; }
__device__ __forceinline__ f4 shp5(f4 v){ return { dppf<CTL_SHL1>(v.y), dppf<CTL_SHL1>(v.z),
                                                   dppf<CTL_SHL1>(v.w), dppf<CTL_SHL2>(v.x) }; }
__device__ __forceinline__ f4 shm5(f4 v){ return { dppf<CTL_SHR2>(v.w), dppf<CTL_SHR1>(v.x),
                                                   dppf<CTL_SHR1>(v.y), dppf<CTL_SHR1>(v.z) }; }

__device__ __forceinline__ f4 prelu_acc(f4 acc, f4 y, float a) {
    acc.x += fmaxf(y.x, 0.f) + a * fminf(y.x, 0.f);
    acc.y += fmaxf(y.y, 0.f) + a * fminf(y.y, 0.f);
    acc.z += fmaxf(y.z, 0.f) + a * fminf(y.z, 0.f);
    acc.w += fmaxf(y.w, 0.f) + a * fminf(y.w, 0.f);
    return acc;
}

// ---- prep: fold params into packed 36-float records (d_ws) ----
__global__ void prep_kernel(const float* __restrict__ bias,
                            const float* __restrict__ conv_w,
                            const float* __restrict__ conv_b,
                            const float* __restrict__ move1,
                            const float* __restrict__ alpha,
                            const float* __restrict__ move2,
                            const float* __restrict__ ln_g,
                            const float* __restrict__ ln_b,
                            float* __restrict__ pp, float* __restrict__ gb) {
    const int c = threadIdx.x;
    if (c >= C) return;
    float* pc = pp + c * PPS;
    #pragma unroll
    for (int i = 0; i < 3; ++i)
        #pragma unroll
        for (int k = 0; k < 9; ++k)
            pc[i * 9 + k] = conv_w[(size_t)(i * C + c) * 9 + k];
    #pragma unroll
    for (int i = 0; i < 3; ++i) {
        pc[27 + i] = conv_b[i * C + c] - move1[i * C + c];
        pc[30 + i] = alpha[i * C + c];
    }
    pc[33] = bias[c];
    pc[34] = move2[0 * C + c] + move2[1 * C + c] + move2[2 * C + c];
    pc[35] = 0.f;
    gb[2 * c]     = ln_g[c];
    gb[2 * c + 1] = ln_b[c];
}

// One channel-iteration, textually inlined. JV = this step's channel index
// (0..11, wave-rotated), JN = the NEXT step's channel index (prefetch
// target). cur[] must already hold channel JV's rows.
#define STEP_BODY(JV, JN, DO_PF, ACC_OUT)                                    \
    {                                                                        \
        const float* pc_ = pp + (cbase + 4 * (JV)) * PPS;                    \
        float wf[36];                                                        \
        _Pragma("unroll")                                                    \
        for (int k = 0; k < 9; ++k)                                          \
            *(f4*)(wf + 4 * k) = *(const f4*)(pc_ + 4 * k);                  \
        if (DO_PF) {                                                         \
            const float* xn_ = xc + (size_t)(4 * (JN)) * HW;                 \
            _Pragma("unroll")                                                \
            for (int k = 0; k < 7; ++k)                                      \
                nxt[k] = vr[k] ? *(const f4*)(xn_ + ro[k]) : f4z();          \
        }                                                                    \
        const float bsa_ = wf[33] * act_f;                                   \
        f4 r[7];                                                             \
        _Pragma("unroll")                                                    \
        for (int k = 0; k < 7; ++k) {                                        \
            const float bk_ = vr[k] ? bsa_ : 0.f;                            \
            r[k].x = fmaf(cur[k].x, act_f, bk_);                             \
            r[k].y = fmaf(cur[k].y, act_f, bk_);                             \
            r[k].z = fmaf(cur[k].z, act_f, bk_);                             \
            r[k].w = fmaf(cur[k].w, act_f, bk_);                             \
        }                                                                    \
        f4 acc_ = f4b(wf[34]);                                               \
        {   /* d = 1 */                                                      \
            f4 y = f4b(wf[27]);                                              \
            y = fma4(shm1(r[2]), wf[0], y);                                  \
            y = fma4(r[2],       wf[1], y);                                  \
            y = fma4(shp1(r[2]), wf[2], y);                                  \
            y = fma4(shm1(r[3]), wf[3], y);                                  \
            y = fma4(r[3],       wf[4], y);                                  \
            y = fma4(shp1(r[3]), wf[5], y);                                  \
            y = fma4(shm1(r[4]), wf[6], y);                                  \
            y = fma4(r[4],       wf[7], y);                                  \
            y = fma4(shp1(r[4]), wf[8], y);                                  \
            acc_ = prelu_acc(acc_, y, wf[30]);                               \
        }                                                                    \
        {   /* d = 3 */                                                      \
            f4 y = f4b(wf[28]);                                              \
            y = fma4(shm3(r[1]), wf[9],  y);                                 \
            y = fma4(r[1],       wf[10], y);                                 \
            y = fma4(shp3(r[1]), wf[11], y);                                 \
            y = fma4(shm3(r[3]), wf[12], y);                                 \
            y = fma4(r[3],       wf[13], y);                                 \
            y = fma4(shp3(r[3]), wf[14], y);                                 \
            y = fma4(shm3(r[5]), wf[15], y);                                 \
            y = fma4(r[5],       wf[16], y);                                 \
            y = fma4(shp3(r[5]), wf[17], y);                                 \
            acc_ = prelu_acc(acc_, y, wf[31]);                               \
        }                                                                    \
        {   /* d = 5 */                                                      \
            f4 y = f4b(wf[29]);                                              \
            y = fma4(shm5(r[0]), wf[18], y);                                 \
            y = fma4(r[0],       wf[19], y);                                 \
            y = fma4(shp5(r[0]), wf[20], y);                                 \
            y = fma4(shm5(r[3]), wf[21], y);                                 \
            y = fma4(r[3],       wf[22], y);                                 \
            y = fma4(shp5(r[3]), wf[23], y);                                 \
            y = fma4(shm5(r[6]), wf[24], y);                                 \
            y = fma4(r[6],       wf[25], y);                                 \
            y = fma4(shp5(r[6]), wf[26], y);                                 \
            acc_ = prelu_acc(acc_, y, wf[32]);                               \
        }                                                                    \
        s4.x += acc_.x; s4.y += acc_.y; s4.z += acc_.z; s4.w += acc_.w;      \
        q4.x = fmaf(acc_.x, acc_.x, q4.x); q4.y = fmaf(acc_.y, acc_.y, q4.y);\
        q4.z = fmaf(acc_.z, acc_.z, q4.z); q4.w = fmaf(acc_.w, acc_.w, q4.w);\
        (ACC_OUT) = acc_;                                                    \
    }

#define ROTATE_CUR()                                                         \
    _Pragma("unroll")                                                        \
    for (int k = 0; k < 7; ++k) cur[k] = nxt[k];

// r7 lesson: hipcc's VGPR cap = 256/N for launch_bounds(256,N) (measured:
// N=5->48, N=4->64, N=3->84). Pipelining in registers can't fit any tier.
// r0/r4/r6 accounting: per step a wave issues ~540cy of VALU in ~2700cy of
// wall (~80% stall), and VALUBusy is pinned at 42% regardless of 27% vs 36%
// occupancy -> waves stall in LOCKSTEP (same loop, same instants, same
// bursts). This round desynchronizes phases for free: wave-rotated channel
// order off=3*((wv+blk)&3); one wave's load latency is covered by another
// wave's FMA burst. No new registers, no new traffic. launch_bounds(256,3)
// (cap 84) gives slack over the ~72 regs needed; runtime occupancy stays
// 4 blocks/CU via LDS 37888 + <=128-reg tier.
__global__ __launch_bounds__(256, 3) void msgdc_kernel(
    const float* __restrict__ x, const float* __restrict__ pp,
    const float* __restrict__ gb, float* __restrict__ out)
{
    __shared__ float tile[160 * W];      // 35840 B: local steps 0..9 stash
    __shared__ float sred[4][16][8];     // cross-wave LN partials (2048 B)

    const int t = threadIdx.x;
    const int lane = t & 63;
    const int wv = __builtin_amdgcn_readfirstlane(t >> 6);
    const int l = lane & 15;             // position within 16-lane sub-group
    const int tix = wv * 4 + (lane >> 4);  // sub-group id 0..15
    const bool act = (l < 14);           // 14 lanes x float4 = 56 pixels
    const float act_f = act ? 1.f : 0.f;
    const int lw = act ? 4 * l : 52;     // clamped (safe) w offset for idle lanes

    const int blk = blockIdx.x;
    const int gid = (blk & 7) * 224 + (blk >> 3);   // XCD-contiguous (b,h)
    const int b = gid / H;
    const int h = gid - b * H;

    // per-wave phase rotation: wave handles channel-steps off, off+1, ... mod 12
    const int off = 3 * ((wv + blk) & 3);

    // uniform row validity, offsets {-5,-3,-1,0,+1,+3,+5}
    const bool vr[7] = { h >= 5, h >= 3, h >= 1, true,
                         h <= H - 2, h <= H - 4, h <= H - 6 };
    const int  ro[7] = { -5 * W, -3 * W, -1 * W, 0, 1 * W, 3 * W, 5 * W };

    const int cbase = wv * 48 + (lane >> 4);        // channel for step 0
    const float* xc = x + (size_t)b * CHW + (size_t)cbase * HW + h * W + lw;

    f4 cur[7], nxt[7];
    {   // prologue: rows for the wave's FIRST step (channel cbase+4*off)
        const float* x0 = xc + (size_t)(4 * off) * HW;
        #pragma unroll
        for (int k = 0; k < 7; ++k)
            nxt[k] = vr[k] ? *(const f4*)(x0 + ro[k]) : f4z();
    }

    f4 s4 = f4z(), q4 = f4z();

    // local steps 0..9: stash pre-LN in LDS at per-wave-private slot j
    #pragma unroll 2
    for (int j = 0; j < 10; ++j) {
        int jj = j + off;     if (jj >= 12) jj -= 12;   // this step's channel
        int jn = jj + 1;      if (jn >= 12) jn -= 12;   // next step's channel
        ROTATE_CUR();
        f4 acc;
        STEP_BODY(jj, jn, true, acc);
        if (act) *(f4*)(tile + (tix * 10 + j) * W + lw) = acc;
    }
    // local steps 10..11: pre-LN values in NAMED registers (post-loop only)
    int jj10 = 10 + off; if (jj10 >= 12) jj10 -= 12;
    int jj11 = 11 + off; if (jj11 >= 12) jj11 -= 12;
    f4 acc_r0, acc_r1;
    __builtin_amdgcn_sched_barrier(0);
    { ROTATE_CUR(); STEP_BODY(jj10, jj11, true, acc_r0); }
    __builtin_amdgcn_sched_barrier(0);
    { ROTATE_CUR(); STEP_BODY(jj11, jj11, false, acc_r1); }
    __builtin_amdgcn_sched_barrier(0);

    // ---- LN reduction: cross-group (xor16/32 keeps l fixed), then cross-wave ----
    #pragma unroll
    for (int m = 16; m <= 32; m <<= 1) {
        s4.x += __shfl_xor(s4.x, m, 64); s4.y += __shfl_xor(s4.y, m, 64);
        s4.z += __shfl_xor(s4.z, m, 64); s4.w += __shfl_xor(s4.w, m, 64);
        q4.x += __shfl_xor(q4.x, m, 64); q4.y += __shfl_xor(q4.y, m, 64);
        q4.z += __shfl_xor(q4.z, m, 64); q4.w += __shfl_xor(q4.w, m, 64);
    }
    if (lane < 14) {
        *(f4*)&sred[wv][lane][0] = s4;
        *(f4*)&sred[wv][lane][4] = q4;
    }
    __syncthreads();

    f4 S = f4z(), Q = f4z();
    #pragma unroll
    for (int w2 = 0; w2 < 4; ++w2) {
        const f4 a = *(const f4*)&sred[w2][l][0];
        const f4 bq = *(const f4*)&sred[w2][l][4];
        S.x += a.x; S.y += a.y; S.z += a.z; S.w += a.w;
        Q.x += bq.x; Q.y += bq.y; Q.z += bq.z; Q.w += bq.w;
    }
    const float inv = 1.f / (float)C;
    f4 mean = { S.x * inv, S.y * inv, S.z * inv, S.w * inv };
    f4 rstd = { rsqrtf(Q.x * inv - mean.x * mean.x + EPSLN),
                rsqrtf(Q.y * inv - mean.y * mean.y + EPSLN),
                rsqrtf(Q.z * inv - mean.z * mean.z + EPSLN),
                rsqrtf(Q.w * inv - mean.w * mean.w + EPSLN) };

    float* ob = out + (size_t)b * CHW + (size_t)cbase * HW + h * W + lw;
    // local steps 0..9 from LDS (channel = cbase + 4*jj, slot = local j)
    #pragma unroll 2
    for (int j = 0; j < 10; ++j) {
        int jj = j + off; if (jj >= 12) jj -= 12;
        const int c = cbase + 4 * jj;
        const float ga = gb[2 * c], be = gb[2 * c + 1];
        if (act) {
            const f4 v = *(const f4*)(tile + (tix * 10 + j) * W + lw);
            f4 o;
            o.x = fmaf((v.x - mean.x) * rstd.x, ga, be);
            o.y = fmaf((v.y - mean.y) * rstd.y, ga, be);
            o.z = fmaf((v.z - mean.z) * rstd.z, ga, be);
            o.w = fmaf((v.w - mean.w) * rstd.w, ga, be);
            *(f4*)(ob + (size_t)(4 * jj) * HW) = o;
        }
    }
    // local steps 10..11 from named registers
#define LN_REG_STORE(JJV, ACCV)                                              \
    {                                                                        \
        const int c_ = cbase + 4 * (JJV);                                    \
        const float ga_ = gb[2 * c_], be_ = gb[2 * c_ + 1];                  \
        if (act) {                                                           \
            const f4 v = (ACCV);                                             \
            f4 o;                                                            \
            o.x = fmaf((v.x - mean.x) * rstd.x, ga_, be_);                   \
            o.y = fmaf((v.y - mean.y) * rstd.y, ga_, be_);                   \
            o.z = fmaf((v.z - mean.z) * rstd.z, ga_, be_);                   \
            o.w = fmaf((v.w - mean.w) * rstd.w, ga_, be_);                   \
            *(f4*)(ob + (size_t)(4 * (JJV)) * HW) = o;                       \
        }                                                                    \
    }
    LN_REG_STORE(jj10, acc_r0);
    LN_REG_STORE(jj11, acc_r1);
#undef LN_REG_STORE
}

extern "C" void kernel_launch(void* const* d_in, const int* in_sizes, int n_in,
                              void* d_out, int out_size, void* d_ws, size_t ws_size,
                              hipStream_t stream) {
    const float* x       = (const float*)d_in[0];
    const float* bias    = (const float*)d_in[1];
    const float* conv_w  = (const float*)d_in[2];
    const float* conv_b  = (const float*)d_in[3];
    const float* move1   = (const float*)d_in[4];
    const float* alpha   = (const float*)d_in[5];
    const float* move2   = (const float*)d_in[6];
    const float* ln_g    = (const float*)d_in[7];
    const float* ln_b    = (const float*)d_in[8];
    float* out = (float*)d_out;

    float* pp = (float*)d_ws;                 // 192*36 floats
    float* gbp = pp + C * PPS;                // 192*2 floats

    prep_kernel<<<1, 256, 0, stream>>>(bias, conv_w, conv_b, move1, alpha,
                                       move2, ln_g, ln_b, pp, gbp);
    msgdc_kernel<<<NB * H, 256, 0, stream>>>(x, pp, gbp, out);
}